// Round 4
// baseline (36.111 us; speedup 1.0000x reference)
//
#include <hip/hip_runtime.h>
#include <hip/hip_bf16.h>
#include <math.h>

#define N 1024
#define TB 16

typedef __attribute__((ext_vector_type(8))) short short8;
typedef __attribute__((ext_vector_type(4))) short short4v;
typedef __attribute__((ext_vector_type(4))) float f32x4;

// PReLU via max/min: max(v,0) + a*min(v,0)
__device__ __forceinline__ float prelu(float v, float a) {
    return fmaxf(v, 0.f) + a * fminf(v, 0.f);
}

// f32 -> bf16 RNE via hardware cvt (compiler pairs into v_cvt_pk_bf16_f32)
__device__ __forceinline__ short f2bf(float f) {
    return (short)__bfloat16_as_ushort(__float2bfloat16(f));
}

__global__ __launch_bounds__(256, 8) void precond_mfma(
    const float* __restrict__ xg, const int* __restrict__ maskg,
    const float* __restrict__ w1, const float* __restrict__ b1, const float* __restrict__ a1p,
    const float* __restrict__ w2, const float* __restrict__ b2, const float* __restrict__ a2p,
    const float* __restrict__ w3, const float* __restrict__ b3, const float* __restrict__ a3p,
    const float* __restrict__ w4, const float* __restrict__ b4p,
    float* __restrict__ out)
{
    const int tid = threadIdx.x;
    const int bz  = blockIdx.z;
    const int ty0 = blockIdx.y * TB, tx0 = blockIdx.x * TB;

    // ---- Early exit: tile entirely above the diagonal -> all zeros ----
    if (blockIdx.y < blockIdx.x) {
        int ty = tid >> 4, tx = tid & 15;
        out[((size_t)bz * N + ty0 + ty) * N + tx0 + tx] = 0.f;
        return;
    }

    __shared__ __align__(16) short sW2[512];        // [oc=16][k=32], k = khkw*8 + ic
    __shared__ __align__(16) short sW3[1024];       // [oc=16][k=64], k = khkw*16 + ic (oc>=8 zero)
    __shared__ __align__(16) short h1s[324 * 8];    // [pos 18x18][8ch] bf16, 16B/pos
    __shared__ __align__(16) short h2lo[289 * 8];   // [pos 17x17][ch 0-7]  bf16, 16B/pos
    __shared__ __align__(16) short h2hi[289 * 8];   // [pos 17x17][ch 8-15] bf16, 16B/pos
    __shared__ unsigned short msu[324];             // mask at h1 positions (0/1)
    __shared__ unsigned short m2su[289];            // spread mask at h2 positions
    __shared__ unsigned short m3su[256];            // spread mask at output pixels

    const float a1 = a1p[0], a2 = a2p[0], a3 = a3p[0];

    // --- stage transposed bf16 weights ---
    for (int t = tid; t < 512; t += 256) {
        int o = t >> 5, khkw = (t >> 3) & 3, i = t & 7;
        sW2[t] = f2bf(w2[((o * 8 + i) * 2 + (khkw >> 1)) * 2 + (khkw & 1)]);
    }
    for (int t = tid; t < 1024; t += 256) {
        int oc = t >> 6, k = t & 63, khkw = k >> 4, i = k & 15;
        sW3[t] = (oc < 8) ? f2bf(w3[((oc * 16 + i) * 2 + (khkw >> 1)) * 2 + (khkw & 1)]) : (short)0;
    }

    // --- Phase A: h1 (masked, PReLU'd, bf16) + mask into LDS (18x18 halo) ---
    for (int p = tid; p < 324; p += 256) {
        int dy = p / 18, dx = p - dy * 18;
        int gy = ty0 - 1 + dy, gx = tx0 - 1 + dx;
        float mv = 0.f, xv = 0.f;
        if ((unsigned)gy < N && (unsigned)gx < N) {
            size_t idx = ((size_t)bz * N + gy) * N + gx;
            mv = (maskg[idx] > 0) ? 1.f : 0.f;
            xv = xg[idx];
        }
        msu[p] = (unsigned short)(mv != 0.f);
        short8 hv;
#pragma unroll
        for (int c = 0; c < 8; ++c) hv[c] = f2bf(mv * prelu(fmaf(xv, w1[c], b1[c]), a1));
        *(short8*)&h1s[p * 8] = hv;
    }
    __syncthreads();

    // --- m2 pre-pass: spread mask at h2 positions (once per position) ---
    for (int p = tid; p < 289; p += 256) {
        int dy2 = p / 17, dx2 = p - dy2 * 17;
        unsigned m2 = (unsigned)(msu[dy2 * 18 + dx2]       | msu[dy2 * 18 + dx2 + 1] |
                                 msu[(dy2 + 1) * 18 + dx2] | msu[(dy2 + 1) * 18 + dx2 + 1]);
        int gx2 = tx0 - 1 + dx2;                 // valid output col range [0, N-2]
        if ((unsigned)gx2 > (unsigned)(N - 2)) m2 = 0;
        m2su[p] = (unsigned short)m2;
    }
    __syncthreads();

    const int lane = tid & 63, wid = tid >> 6;
    const int c16 = lane & 15, g = lane >> 4;

    // --- Phase B: h2 at 17x17 positions via MFMA (K=32: 4 khkw x 8 ic) ---
    {
        short8 a2f = *(const short8*)&sW2[c16 * 32 + g * 8];
        const int kh = g >> 1, kw = g & 1;
        f32x4 bias2;
#pragma unroll
        for (int r = 0; r < 4; ++r) bias2[r] = b2[g * 4 + r];

        for (int G = wid * 5; G < wid * 5 + 5; ++G) {   // 20 groups of 16 positions
            int p = G * 16 + c16;
            bool valid = p < 289;
            int pc = valid ? p : 288;
            int dy2 = pc / 17, dx2 = pc - dy2 * 17;
            short8 bf = *(const short8*)&h1s[((dy2 + kh) * 18 + dx2 + kw) * 8];
            f32x4 acc = __builtin_amdgcn_mfma_f32_16x16x32_bf16(a2f, bf, bias2, 0, 0, 0);
            float pm = (m2su[pc] != 0) ? 1.f : 0.f;
            if (valid) {
                short4v hv;
#pragma unroll
                for (int r = 0; r < 4; ++r) hv[r] = f2bf(pm * prelu(acc[r], a2));
                short* dst = (g & 2) ? (short*)h2hi : (short*)h2lo;
                *(short4v*)&dst[pc * 8 + (g & 1) * 4] = hv;
            }
        }
    }

    // --- m3 pre-pass: spread mask at output pixels (reads m2su, ready pre-B) ---
    {
        int ty = tid >> 4, tx = tid & 15;
        m3su[tid] = (unsigned short)(m2su[ty * 17 + tx]       | m2su[ty * 17 + tx + 1] |
                                     m2su[(ty + 1) * 17 + tx] | m2su[(ty + 1) * 17 + tx + 1]);
    }
    __syncthreads();

    // --- Phase C: h3 via 2 chained MFMAs (K=64) + layer4 + epilogue ---
    {
        short8 a3f0 = *(const short8*)&sW3[c16 * 64 + g * 8];        // k 0..31  (kh=0)
        short8 a3f1 = *(const short8*)&sW3[c16 * 64 + 32 + g * 8];   // k 32..63 (kh=1)
        const int kw = g >> 1, ic8 = g & 1;
        const short* h2sel = ic8 ? (const short*)h2hi : (const short*)h2lo;
        f32x4 bias3;
        float w4r[4];
#pragma unroll
        for (int r = 0; r < 4; ++r) {
            bias3[r] = (g < 2) ? b3[g * 4 + r] : 0.f;
            w4r[r]   = (g < 2) ? w4[g * 4 + r] : 0.f;
        }
        const float b4 = b4p[0];

        for (int G = wid * 4; G < wid * 4 + 4; ++G) {   // 16 output rows
            short8 bf0 = *(const short8*)&h2sel[((G + 0) * 17 + c16 + kw) * 8];
            short8 bf1 = *(const short8*)&h2sel[((G + 1) * 17 + c16 + kw) * 8];
            f32x4 acc = __builtin_amdgcn_mfma_f32_16x16x32_bf16(a3f0, bf0, bias3, 0, 0, 0);
            acc = __builtin_amdgcn_mfma_f32_16x16x32_bf16(a3f1, bf1, acc, 0, 0, 0);

            float partial = 0.f;
#pragma unroll
            for (int r = 0; r < 4; ++r) partial = fmaf(prelu(acc[r], a3), w4r[r], partial);
            partial += __shfl_xor(partial, 16, 64);
            partial += __shfl_xor(partial, 32, 64);

            if (g == 0) {
                bool m3 = m3su[G * 16 + c16] != 0;
                float outv = m3 ? (partial + b4) : 0.f;
                int y = ty0 + G, x = tx0 + c16;
                if (y < x) {
                    outv = 0.f;
                } else if (y == x && m3) {
                    outv = fmaxf(outv, 0.f) + log1pf(expf(-fabsf(outv)));
                }
                out[((size_t)bz * N + y) * N + x] = outv;
            }
        }
    }
}

extern "C" void kernel_launch(void* const* d_in, const int* in_sizes, int n_in,
                              void* d_out, int out_size, void* d_ws, size_t ws_size,
                              hipStream_t stream) {
    const float* x    = (const float*)d_in[0];
    const int*   mask = (const int*)  d_in[1];
    const float* w1   = (const float*)d_in[2];
    const float* b1   = (const float*)d_in[3];
    const float* a1   = (const float*)d_in[4];
    const float* w2   = (const float*)d_in[5];
    const float* b2   = (const float*)d_in[6];
    const float* a2   = (const float*)d_in[7];
    const float* w3   = (const float*)d_in[8];
    const float* b3   = (const float*)d_in[9];
    const float* a3   = (const float*)d_in[10];
    const float* w4   = (const float*)d_in[11];
    const float* b4   = (const float*)d_in[12];
    float* out = (float*)d_out;

    dim3 grid(N / TB, N / TB, 2);
    precond_mfma<<<grid, 256, 0, stream>>>(x, mask, w1, b1, a1, w2, b2, a2,
                                           w3, b3, a3, w4, b4, out);
}

// Round 5
// 32.927 us; speedup vs baseline: 1.0967x; 1.0967x over previous
//
#include <hip/hip_runtime.h>
#include <hip/hip_bf16.h>
#include <math.h>

#define N 1024
#define TB 16

typedef __attribute__((ext_vector_type(8))) short short8;
typedef __attribute__((ext_vector_type(4))) short short4v;
typedef __attribute__((ext_vector_type(4))) float f32x4;

// PReLU via max/min: max(v,0) + a*min(v,0)
__device__ __forceinline__ float prelu(float v, float a) {
    return fmaxf(v, 0.f) + a * fminf(v, 0.f);
}

// f32 -> bf16 RNE via hardware cvt (pairs into v_cvt_pk_bf16_f32)
__device__ __forceinline__ short f2bf(float f) {
    return (short)__bfloat16_as_ushort(__float2bfloat16(f));
}

__global__ __launch_bounds__(256, 8) void precond_mfma(
    const float* __restrict__ xg, const int* __restrict__ maskg,
    const float* __restrict__ w1, const float* __restrict__ b1, const float* __restrict__ a1p,
    const float* __restrict__ w2, const float* __restrict__ b2, const float* __restrict__ a2p,
    const float* __restrict__ w3, const float* __restrict__ b3, const float* __restrict__ a3p,
    const float* __restrict__ w4, const float* __restrict__ b4p,
    float* __restrict__ out)
{
    const int tid = threadIdx.x;
    const int bz  = blockIdx.z;
    const int ty0 = blockIdx.y * TB, tx0 = blockIdx.x * TB;

    // ---- Early exit: tile entirely above the diagonal -> all zeros ----
    if (blockIdx.y < blockIdx.x) {
        int ty = tid >> 4, tx = tid & 15;
        out[((size_t)bz * N + ty0 + ty) * N + tx0 + tx] = 0.f;
        return;
    }

    __shared__ __align__(16) short sW2[512];        // [oc=16][k=32], k = khkw*8 + ic
    __shared__ __align__(16) short sW3[1024];       // [oc=16][k=64], k = khkw*16 + ic (oc>=8 zero)
    __shared__ __align__(16) short h1s[324 * 8];    // [pos 18x18][8ch] bf16, 16B/pos
    __shared__ __align__(16) short h2lo[289 * 8];   // [pos 17x17][ch 0-7]  bf16, 16B/pos
    __shared__ __align__(16) short h2hi[289 * 8];   // [pos 17x17][ch 8-15] bf16, 16B/pos
    __shared__ unsigned short msu[324];             // layer-1 mask (0/1) at h1 positions
    __shared__ unsigned short m2su[289];            // spread mask at h2 positions

    const float a1 = a1p[0], a2 = a2p[0], a3 = a3p[0];
    const bool leftEdge  = (tx0 == 0);
    const bool rightEdge = (tx0 == N - TB);

    // --- stage transposed bf16 weights ---
    for (int t = tid; t < 512; t += 256) {
        int o = t >> 5, khkw = (t >> 3) & 3, i = t & 7;
        sW2[t] = f2bf(w2[((o * 8 + i) * 2 + (khkw >> 1)) * 2 + (khkw & 1)]);
    }
    for (int t = tid; t < 1024; t += 256) {
        int oc = t >> 6, k = t & 63, khkw = k >> 4, i = k & 15;
        sW3[t] = (oc < 8) ? f2bf(w3[((oc * 16 + i) * 2 + (khkw >> 1)) * 2 + (khkw & 1)]) : (short)0;
    }

    // --- Phase A: h1 (masked, PReLU'd, bf16) + mask into LDS (18x18 halo) ---
    for (int p = tid; p < 324; p += 256) {
        int dy = p / 18, dx = p - dy * 18;
        int gy = ty0 - 1 + dy, gx = tx0 - 1 + dx;
        float mv = 0.f, xv = 0.f;
        if ((unsigned)gy < N && (unsigned)gx < N) {
            size_t idx = ((size_t)bz * N + gy) * N + gx;
            mv = (maskg[idx] > 0) ? 1.f : 0.f;
            xv = xg[idx];
        }
        msu[p] = (unsigned short)(mv != 0.f);
        short8 hv;
#pragma unroll
        for (int c = 0; c < 8; ++c) hv[c] = f2bf(mv * prelu(fmaf(xv, w1[c], b1[c]), a1));
        *(short8*)&h1s[p * 8] = hv;
    }
    __syncthreads();

    const int lane = tid & 63, wid = tid >> 6;
    const int c16 = lane & 15, g = lane >> 4;

    // --- Phase B: h2 at 17x17 positions via MFMA (K=32: 4 khkw x 8 ic) ---
    // 19 groups of 16 positions: wave w handles {w, w+4, w+8, w+12} and (w<3) {16+w}.
    {
        short8 a2f = *(const short8*)&sW2[c16 * 32 + g * 8];
        const int kh = g >> 1, kw = g & 1;
        f32x4 bias2;
#pragma unroll
        for (int r = 0; r < 4; ++r) bias2[r] = b2[g * 4 + r];

#pragma unroll
        for (int k = 0; k < 5; ++k) {
            if (k == 4 && wid == 3) break;            // wave-uniform
            const int grp = (k < 4) ? (wid + 4 * k) : (16 + wid);
            int p = grp * 16 + c16;
            bool valid = p < 289;
            int pc = valid ? p : 288;
            int dy2 = pc / 17, dx2 = pc - dy2 * 17;

            short8 bf = *(const short8*)&h1s[((dy2 + kh) * 18 + dx2 + kw) * 8];
            f32x4 acc = __builtin_amdgcn_mfma_f32_16x16x32_bf16(a2f, bf, bias2, 0, 0, 0);

            // spread mask (integer ORs) + hoisted edge-column invalidation
            int mb = dy2 * 18 + dx2;
            unsigned m2 = (unsigned)(msu[mb] | msu[mb + 1] | msu[mb + 18] | msu[mb + 19]);
            if ((leftEdge && dx2 == 0) || (rightEdge && dx2 == 16)) m2 = 0;

            short4v hv;
#pragma unroll
            for (int r = 0; r < 4; ++r) hv[r] = f2bf(prelu(acc[r], a2));
            if (m2 == 0) { hv[0] = 0; hv[1] = 0; hv[2] = 0; hv[3] = 0; }

            if (valid) {
                short* dst = (g & 2) ? (short*)h2hi : (short*)h2lo;
                *(short4v*)&dst[pc * 8 + (g & 1) * 4] = hv;
                if (g == 0) m2su[pc] = (unsigned short)(m2 != 0);
            }
        }
    }
    __syncthreads();

    // --- Phase C: h3 via 2 chained MFMAs (K=64) + layer4 + epilogue ---
    {
        short8 a3f0 = *(const short8*)&sW3[c16 * 64 + g * 8];        // k 0..31  (kh=0)
        short8 a3f1 = *(const short8*)&sW3[c16 * 64 + 32 + g * 8];   // k 32..63 (kh=1)
        const int kw = g >> 1, ic8 = g & 1;
        const short* h2sel = ic8 ? (const short*)h2hi : (const short*)h2lo;
        f32x4 bias3;
        float w4r[4];
#pragma unroll
        for (int r = 0; r < 4; ++r) {
            bias3[r] = (g < 2) ? b3[g * 4 + r] : 0.f;
            w4r[r]   = (g < 2) ? w4[g * 4 + r] : 0.f;
        }
        const float b4 = b4p[0];

#pragma unroll
        for (int j = 0; j < 4; ++j) {                 // 16 output rows, 4 per wave
            const int G = wid * 4 + j;
            short8 bf0 = *(const short8*)&h2sel[((G + 0) * 17 + c16 + kw) * 8];
            short8 bf1 = *(const short8*)&h2sel[((G + 1) * 17 + c16 + kw) * 8];
            f32x4 acc = __builtin_amdgcn_mfma_f32_16x16x32_bf16(a3f0, bf0, bias3, 0, 0, 0);
            acc = __builtin_amdgcn_mfma_f32_16x16x32_bf16(a3f1, bf1, acc, 0, 0, 0);

            float partial = 0.f;
#pragma unroll
            for (int r = 0; r < 4; ++r) partial = fmaf(prelu(acc[r], a3), w4r[r], partial);
            partial += __shfl_xor(partial, 16, 64);
            partial += __shfl_xor(partial, 32, 64);

            if (g == 0) {
                int mb = G * 17 + c16;
                unsigned m3 = (unsigned)(m2su[mb] | m2su[mb + 1] | m2su[mb + 17] | m2su[mb + 18]);
                float outv = m3 ? (partial + b4) : 0.f;
                int y = ty0 + G, x = tx0 + c16;
                if (y < x) {
                    outv = 0.f;
                } else if (y == x && m3) {
                    outv = fmaxf(outv, 0.f) + log1pf(expf(-fabsf(outv)));
                }
                out[((size_t)bz * N + y) * N + x] = outv;
            }
        }
    }
}

extern "C" void kernel_launch(void* const* d_in, const int* in_sizes, int n_in,
                              void* d_out, int out_size, void* d_ws, size_t ws_size,
                              hipStream_t stream) {
    const float* x    = (const float*)d_in[0];
    const int*   mask = (const int*)  d_in[1];
    const float* w1   = (const float*)d_in[2];
    const float* b1   = (const float*)d_in[3];
    const float* a1   = (const float*)d_in[4];
    const float* w2   = (const float*)d_in[5];
    const float* b2   = (const float*)d_in[6];
    const float* a2   = (const float*)d_in[7];
    const float* w3   = (const float*)d_in[8];
    const float* b3   = (const float*)d_in[9];
    const float* a3   = (const float*)d_in[10];
    const float* w4   = (const float*)d_in[11];
    const float* b4   = (const float*)d_in[12];
    float* out = (float*)d_out;

    dim3 grid(N / TB, N / TB, 2);
    precond_mfma<<<grid, 256, 0, stream>>>(x, mask, w1, b1, a1, w2, b2, a2,
                                           w3, b3, a3, w4, b4, out);
}